// Round 8
// baseline (671.144 us; speedup 1.0000x reference)
//
#include <hip/hip_runtime.h>
#include <math.h>

// Problem dims (fixed by reference)
#define BB   8
#define TT   2048
#define CIN  512
#define DD   1024
#define MM   (BB * TT)     // 16384 rows for the GEMMs

// K1 GEMM tiling: 128x64 block tile, 256 threads, 8x4 dual micro-tile.
// ROUND-1 LESSON: 128-acc microtile spills (VGPR capped at 128; WRITE_SIZE 4x).
// ROUND-2 LESSON: explicit LDS double-buffer halves occupancy, 483->695us.
// ROUND-7 LESSON: lgkm-only barriers DON'T help k1 — the staging ds_write
// consumes the prefetched regs right after the barrier, so the vmcnt(0) wait
// just moves there; the "memory" clobber also pessimizes scheduling (-24us).
// k1 stays EXACTLY the round-0 2-barrier __syncthreads loop at 92 VGPR.
constexpr int BM = 128;
constexpr int BN = 64;
constexpr int BK = 16;

// K2+K3 fused scan+LN: 2 features/thread (float2), h_post never hits HBM.
// ROUND-7 LESSON: lgkm-only barriers DO help k23 (-11us) — loads are consumed
// a full batch after issue, so they genuinely stay in flight across barriers.
// ROUND-8: NCHUNK 32->64 => 512 blocks = 2 blocks/CU (LDS 2x34.8KB fits).
// At 1 block/CU the reduce/barrier phases left the memory pipes idle; a
// co-resident second block fills those gaps.  Warm-read amplification 2.95x
// is mostly L3-served (a_ws/b_ws = 134MB < 256MB Infinity Cache).
// WARM=64: contamination = h_start*exp(-sum delta*A); sum of 64 softplus(N(0,1))
// ~ N(45,6.4), P(sum<9) ~ 5.6 sigma -> error <= ~1e-4 worst plausible.
// ntot per chunk: 4 (chunk0), 8 (chunk1), 12 (rest) — all even.
#define NCHUNK 64
#define CLEN   (TT / NCHUNK)   // 32
#define WARM   64
#define PF     8

// LDS-only barrier: waits LDS ops, leaves global loads/stores in flight.
// Use ONLY where loaded registers are not consumed immediately after the
// barrier (k23 yes, k1 no — see round-7 lesson).
__device__ __forceinline__ void lgkm_bar() {
    asm volatile("s_waitcnt lgkmcnt(0)" ::: "memory");
    __builtin_amdgcn_s_barrier();
}

// softplus(z) = logaddexp(z, 0) — matches jax.nn.softplus / np.logaddexp
__device__ __forceinline__ float softplus_f(float z) {
    return fmaxf(z, 0.f) + log1pf(expf(-fabsf(z)));
}

// K1: fused dual GEMM  zd = x@Wd, zb = x@Wb  (+bias)  →  a_step, b_step
__global__ __launch_bounds__(256) void k1_gemm_act(
    const float* __restrict__ x,      // [MM, CIN]
    const float* __restrict__ Wd,     // [CIN, DD]
    const float* __restrict__ Wb,     // [CIN, DD]
    const float* __restrict__ bd,     // [DD]
    const float* __restrict__ bb,     // [DD]
    const float* __restrict__ A_log,  // [DD]
    float* __restrict__ a_out,        // [MM, DD]
    float* __restrict__ b_out)        // [MM, DD]
{
    // xs transposed: xs[k][m] -> x-fragments are b128 reads; scatter stores 2-way (free).
    __shared__ float xs[BK][BM + 4];
    __shared__ float wds[BK][BN];
    __shared__ float wbs[BK][BN];

    const int tid = threadIdx.x;
    const int n0  = blockIdx.x * BN;
    const int m0  = blockIdx.y * BM;
    const int tx  = tid & 15;          // col group: 4 cols each
    const int ty  = tid >> 4;          // row group: 8 rows each

    // staging indices
    const int lm = tid >> 1;           // 0..127  x row
    const int lk = (tid & 1) * 8;      // 0 or 8  (two float4 = 8 k)
    const int wr = tid >> 4;           // 0..15   w row
    const int wc = (tid & 15) * 4;     // 0..60   w col

    float accd[8][4], accb[8][4];
#pragma unroll
    for (int r = 0; r < 8; ++r)
#pragma unroll
        for (int c = 0; c < 4; ++c) { accd[r][c] = 0.f; accb[r][c] = 0.f; }

    // ---- preload tile 0 into registers ----
    const float* xp  = x + (size_t)(m0 + lm) * CIN + lk;
    const float* wdp = Wd + (size_t)wr * DD + n0 + wc;
    const float* wbp = Wb + (size_t)wr * DD + n0 + wc;
    float4 xva = *(const float4*)(xp);
    float4 xvb = *(const float4*)(xp + 4);
    float4 wd0 = *(const float4*)(wdp);
    float4 wb0 = *(const float4*)(wbp);

    for (int k0 = 0; k0 < CIN; k0 += BK) {
        __syncthreads();   // previous tile's compute done
        xs[lk + 0][lm] = xva.x;  xs[lk + 1][lm] = xva.y;
        xs[lk + 2][lm] = xva.z;  xs[lk + 3][lm] = xva.w;
        xs[lk + 4][lm] = xvb.x;  xs[lk + 5][lm] = xvb.y;
        xs[lk + 6][lm] = xvb.z;  xs[lk + 7][lm] = xvb.w;
        *(float4*)&wds[wr][wc] = wd0;
        *(float4*)&wbs[wr][wc] = wb0;
        __syncthreads();

        // issue next tile's global loads (in flight during compute)
        const int kn = k0 + BK;
        if (kn < CIN) {
            xva = *(const float4*)(xp + kn);
            xvb = *(const float4*)(xp + kn + 4);
            wd0 = *(const float4*)(wdp + (size_t)kn * DD);
            wb0 = *(const float4*)(wbp + (size_t)kn * DD);
        }

#pragma unroll
        for (int kk = 0; kk < BK; ++kk) {
            float4 xa  = *(const float4*)&xs[kk][ty * 8];
            float4 xa2 = *(const float4*)&xs[kk][ty * 8 + 4];
            float4 d0  = *(const float4*)&wds[kk][tx * 4];
            float4 c0  = *(const float4*)&wbs[kk][tx * 4];
            float xr[8] = {xa.x, xa.y, xa.z, xa.w, xa2.x, xa2.y, xa2.z, xa2.w};
            float wd[4] = {d0.x, d0.y, d0.z, d0.w};
            float wb[4] = {c0.x, c0.y, c0.z, c0.w};
#pragma unroll
            for (int r = 0; r < 8; ++r) {
                const float xi = xr[r];
#pragma unroll
                for (int c = 0; c < 4; ++c) {
                    accd[r][c] = fmaf(xi, wd[c], accd[r][c]);
                    accb[r][c] = fmaf(xi, wb[c], accb[r][c]);
                }
            }
        }
    }

    // ---- epilogue ----
    const int nc0 = n0 + tx * 4;
    float4 bdq = *(const float4*)(bd + nc0);
    float4 bbq = *(const float4*)(bb + nc0);
    float4 alq = *(const float4*)(A_log + nc0);
    const float* bdv = (const float*)&bdq;
    const float* bbv = (const float*)&bbq;
    float Aq[4] = {expf(alq.x), expf(alq.y), expf(alq.z), expf(alq.w)};

#pragma unroll
    for (int r = 0; r < 8; ++r) {
        const int m = m0 + ty * 8 + r;
        float av[4], bv[4];
#pragma unroll
        for (int j = 0; j < 4; ++j) {
            float zd    = accd[r][j] + bdv[j];
            float delta = softplus_f(zd);
            float zb    = accb[r][j] + bbv[j];
            av[j] = expf(-delta * Aq[j]);
            bv[j] = delta * zb;
        }
        *(float4*)(a_out + (size_t)m * DD + nc0) = make_float4(av[0], av[1], av[2], av[3]);
        *(float4*)(b_out + (size_t)m * DD + nc0) = make_float4(bv[0], bv[1], bv[2], bv[3]);
    }
}

// ---- fused scan + LayerNorm (512 threads, 2 features/thread) ----
// Per output batch (2 lgkm-only barriers):
//   scan PF steps (spikes written inline, h stashed in regs)
//   pre-sum (sum, sumsq) per step -> trans[tid][0..15]   (pad 17: bank-free)
//   PREFETCH next batch (global loads stay in flight across both barriers)
//   bar1 -> 512-thread column sum (rows i2*32+rs: conflict-free, 17 coprime
//           32) + 5-stage shfl over 32 partials -> red[16]
//   bar2 -> ALL threads read red[] (broadcast ds_reads) and compute mu/inv
//           redundantly (identical IEEE expr -> identical values), LN writes
// Hazards (2-barrier proof): trans reads (pre-bar2) vs next trans writes
// (post-bar2) OK; red write (pre-bar2) vs red reads (post-bar2) OK; red reads
// retired by the reader's own lgkmcnt(0) at next bar1, before the next red
// write (post next-bar1) OK.  All branches block-uniform.

#define PREFETCH(AV, BV)                                                  \
    {                                                                     \
        _Pragma("unroll")                                                 \
        for (int j = 0; j < PF; ++j) {                                    \
            AV[j] = *(const float2*)(ap + (size_t)j * DD);                \
            BV[j] = *(const float2*)(bp + (size_t)j * DD);                \
        }                                                                 \
        ap += (size_t)PF * DD; bp += (size_t)PF * DD;                     \
    }

#define WARM_SLOT(AV, BV)                                                 \
    {                                                                     \
        _Pragma("unroll")                                                 \
        for (int j = 0; j < PF; ++j) {                                    \
            h.x = fmaf(AV[j].x, h.x, BV[j].x);                            \
            h.y = fmaf(AV[j].y, h.y, BV[j].y);                            \
            h.x = ((h.x - th.x) > 0.f) ? 0.f : h.x;                       \
            h.y = ((h.y - th.y) > 0.f) ? 0.f : h.y;                       \
        }                                                                 \
    }

#define OUT_SLOT(AV, BV, PFOK)                                            \
    {                                                                     \
        float2 hj[PF];                                                    \
        _Pragma("unroll")                                                 \
        for (int j = 0; j < PF; ++j) {                                    \
            h.x = fmaf(AV[j].x, h.x, BV[j].x);                            \
            h.y = fmaf(AV[j].y, h.y, BV[j].y);                            \
            const bool kx = (h.x - th.x) > 0.f;                           \
            const bool ky = (h.y - th.y) > 0.f;                           \
            *(float2*)(sp + (size_t)j * DD) =                             \
                make_float2(kx ? 1.f : 0.f, ky ? 1.f : 0.f);              \
            h.x = kx ? 0.f : h.x;                                         \
            h.y = ky ? 0.f : h.y;                                         \
            hj[j] = h;                                                    \
        }                                                                 \
        sp += (size_t)PF * DD;                                            \
        _Pragma("unroll")                                                 \
        for (int j = 0; j < PF; ++j) {                                    \
            trans[tid][j]      = hj[j].x + hj[j].y;                       \
            trans[tid][j + PF] = fmaf(hj[j].x, hj[j].x,                   \
                                      hj[j].y * hj[j].y);                 \
        }                                                                 \
        if (PFOK) PREFETCH(AV, BV)                                        \
        lgkm_bar();                                                       \
        {                                                                 \
            float p = 0.f;                                                \
            _Pragma("unroll")                                             \
            for (int i2 = 0; i2 < 16; ++i2)                               \
                p += trans[i2 * 32 + rs][rq];                             \
            p += __shfl_down(p, 16);                                      \
            p += __shfl_down(p, 8);                                       \
            p += __shfl_down(p, 4);                                       \
            p += __shfl_down(p, 2);                                       \
            p += __shfl_down(p, 1);                                       \
            if (rs == 0) red[rq] = p;                                     \
        }                                                                 \
        lgkm_bar();                                                       \
        float mu_[PF], inv_[PF];                                          \
        _Pragma("unroll")                                                 \
        for (int j = 0; j < PF; ++j) {                                    \
            const float mu  = red[j] * (1.0f / DD);                       \
            const float var =                                             \
                fmaxf(red[j + PF] * (1.0f / DD) - mu * mu, 0.f);          \
            mu_[j]  = mu;                                                 \
            inv_[j] = 1.0f / sqrtf(var + 1e-5f);                          \
        }                                                                 \
        _Pragma("unroll")                                                 \
        for (int j = 0; j < PF; ++j) {                                    \
            float2 o;                                                     \
            o.x = (hj[j].x - mu_[j]) * inv_[j] * g.x + be.x;              \
            o.y = (hj[j].y - mu_[j]) * inv_[j] * g.y + be.y;              \
            *(float2*)(op + (size_t)j * DD) = o;                          \
        }                                                                 \
        op += (size_t)PF * DD;                                            \
    }

__global__ __launch_bounds__(512) void k23_scan_ln(
    const float* __restrict__ a,      // [BB, TT, DD]
    const float* __restrict__ b,      // [BB, TT, DD]
    const float* __restrict__ thr,    // [DD]
    const float* __restrict__ gamma,  // [DD]
    const float* __restrict__ beta,   // [DD]
    float* __restrict__ out,          // [BB, TT, DD]
    float* __restrict__ spikes)       // [BB, TT, DD]
{
    const int tid   = threadIdx.x;     // 0..511 — two features per thread
    const int d0    = tid * 2;
    const int chunk = blockIdx.x;      // 0..63
    const int batch = blockIdx.y;      // 0..7
    const int rq    = tid >> 5;        // 0..15: quantity (0..7 sum, 8..15 ssq)
    const int rs    = tid & 31;        // 0..31: summer index within quantity

    const float2 th = *(const float2*)(thr + d0);
    const float2 g  = *(const float2*)(gamma + d0);
    const float2 be = *(const float2*)(beta + d0);

    const int t0    = chunk * CLEN;
    const int nwarm = (t0 < WARM) ? t0 : WARM;   // 0, 32, or 64; chunks 0-1 exact
    const int tw    = t0 - nwarm;
    const int nwb   = nwarm / PF;                // 0, 4, or 8
    const int ntot  = nwb + CLEN / PF;           // 4, 8, or 12 (even)

    const size_t rowbase = (size_t)batch * TT * DD + d0;
    const float* ap = a + rowbase + (size_t)tw * DD;
    const float* bp = b + rowbase + (size_t)tw * DD;
    float* op = out    + rowbase + (size_t)t0 * DD;
    float* sp = spikes + rowbase + (size_t)t0 * DD;

    __shared__ float trans[512][17];   // 34816 B, pad 17 -> bank-conflict-free
    __shared__ float red[2 * PF];

    float2 a0[PF], b0[PF], a1[PF], b1[PF];
    PREFETCH(a0, b0)
    PREFETCH(a1, b1)

    float2 h = make_float2(0.f, 0.f);
    for (int i = 0; i < ntot; i += 2) {
        if (i >= nwb) OUT_SLOT(a0, b0, i + 2 < ntot)
        else { WARM_SLOT(a0, b0) PREFETCH(a0, b0) }

        if (i + 1 >= nwb) OUT_SLOT(a1, b1, i + 3 < ntot)
        else { WARM_SLOT(a1, b1) PREFETCH(a1, b1) }
    }
}

extern "C" void kernel_launch(void* const* d_in, const int* in_sizes, int n_in,
                              void* d_out, int out_size, void* d_ws, size_t ws_size,
                              hipStream_t stream) {
    const float* x     = (const float*)d_in[0];
    const float* Wd    = (const float*)d_in[1];
    const float* bd    = (const float*)d_in[2];
    const float* Wb    = (const float*)d_in[3];
    const float* bb    = (const float*)d_in[4];
    const float* A_log = (const float*)d_in[5];
    const float* thr   = (const float*)d_in[6];
    const float* gamma = (const float*)d_in[7];
    const float* beta  = (const float*)d_in[8];

    float* out    = (float*)d_out;                    // [MM, DD] LN output
    float* spikes = out + (size_t)MM * DD;            // [MM, DD]
    float* a_ws   = (float*)d_ws;                     // [MM, DD]
    float* b_ws   = a_ws + (size_t)MM * DD;           // [MM, DD]

    dim3 g1(DD / BN, MM / BM);                        // (16, 128)
    k1_gemm_act<<<g1, 256, 0, stream>>>(x, Wd, Wb, bd, bb, A_log, a_ws, b_ws);

    dim3 g2(NCHUNK, BB);                              // (64, 8) = 512 blocks, 2/CU
    k23_scan_ln<<<g2, 512, 0, stream>>>(a_ws, b_ws, thr, gamma, beta, out, spikes);
}

// Round 9
// 649.976 us; speedup vs baseline: 1.0326x; 1.0326x over previous
//
#include <hip/hip_runtime.h>
#include <math.h>

// Problem dims (fixed by reference)
#define BB   8
#define TT   2048
#define CIN  512
#define DD   1024
#define MM   (BB * TT)     // 16384 rows for the GEMMs

// K1 GEMM tiling: 128x64 block tile, 256 threads, 8x4 dual micro-tile.
// ROUND-1 LESSON: 128-acc microtile spills (VGPR capped at 128; WRITE_SIZE 4x).
// ROUND-2 LESSON: explicit LDS double-buffer halves occupancy, 483->695us.
// ROUND-7 LESSON: lgkm-only barriers DON'T help k1 (vmcnt wait just moves to
// the staging ds_write; barrier drain is ~free since compute 2000cy > HBM
// 900cy).  Remaining per-tile cost = 2 sync points + pipeline restart.
// ROUND-9: BK 16->32 halves the barrier count (64->32) at same single-buffer
// structure.  Prefetch regs 16->32 VGPR (est total ~115 < 128 cliff); LDS
// 33.3KB still allows 4 blocks/CU.  Tripwires: VGPR<=128, WRITE_SIZE=131MB.
constexpr int BM = 128;
constexpr int BN = 64;
constexpr int BK = 32;

// K2+K3 fused scan+LN: 2 features/thread (float2), h_post never hits HBM.
// ROUND-7 LESSON: lgkm-only barriers help k23 (-11us) — loads consumed a full
// batch after issue genuinely stay in flight across barriers.
// ROUND-8 LESSON: k23 runs at a fixed ~2.8 TB/s duty-cycle ceiling — time is
// proportional to TOTAL BYTES.  NCHUNK=64 raised warm amplification 1.97x ->
// 2.95x and cost exactly that ratio in time.  NCHUNK=32 minimizes
// amplification at adequate parallelism: 256 blocks, k23 = 143us (measured).
#define NCHUNK 32
#define CLEN   (TT / NCHUNK)   // 64
#define WARM   64
#define PF     8

// LDS-only barrier: waits LDS ops, leaves global loads/stores in flight.
// Use ONLY where loaded registers are not consumed immediately after the
// barrier (k23 yes, k1 no — round-7 lesson).
__device__ __forceinline__ void lgkm_bar() {
    asm volatile("s_waitcnt lgkmcnt(0)" ::: "memory");
    __builtin_amdgcn_s_barrier();
}

// softplus(z) = logaddexp(z, 0) — matches jax.nn.softplus / np.logaddexp
__device__ __forceinline__ float softplus_f(float z) {
    return fmaxf(z, 0.f) + log1pf(expf(-fabsf(z)));
}

// K1: fused dual GEMM  zd = x@Wd, zb = x@Wb  (+bias)  →  a_step, b_step
__global__ __launch_bounds__(256) void k1_gemm_act(
    const float* __restrict__ x,      // [MM, CIN]
    const float* __restrict__ Wd,     // [CIN, DD]
    const float* __restrict__ Wb,     // [CIN, DD]
    const float* __restrict__ bd,     // [DD]
    const float* __restrict__ bb,     // [DD]
    const float* __restrict__ A_log,  // [DD]
    float* __restrict__ a_out,        // [MM, DD]
    float* __restrict__ b_out)        // [MM, DD]
{
    // xs transposed: xs[k][m] -> x-fragments are broadcast reads; scatter
    // stores 2-way (free).  w stores have 8-16-way conflicts but are 1/16 of
    // LDS ops (negligible; measured 4.19M counter at BK=16 was this).
    __shared__ float xs[BK][BM + 4];    // 32x132x4 = 16896 B
    __shared__ float wds[BK][BN];       //  8192 B
    __shared__ float wbs[BK][BN];       //  8192 B  -> 33280 B total

    const int tid = threadIdx.x;
    const int n0  = blockIdx.x * BN;
    const int m0  = blockIdx.y * BM;
    const int tx  = tid & 15;          // col group: 4 cols each
    const int ty  = tid >> 4;          // row group: 8 rows each

    // staging indices
    const int lm = tid >> 1;           // 0..127  x row
    const int lk = (tid & 1) * 16;     // 0 or 16 (four float4 = 16 k)
    const int wr = tid >> 3;           // 0..31   w row
    const int wc = (tid & 7) * 8;      // 0..56   w col (two float4)

    float accd[8][4], accb[8][4];
#pragma unroll
    for (int r = 0; r < 8; ++r)
#pragma unroll
        for (int c = 0; c < 4; ++c) { accd[r][c] = 0.f; accb[r][c] = 0.f; }

    // ---- preload tile 0 into registers ----
    const float* xp  = x + (size_t)(m0 + lm) * CIN + lk;
    const float* wdp = Wd + (size_t)wr * DD + n0 + wc;
    const float* wbp = Wb + (size_t)wr * DD + n0 + wc;
    float4 xva = *(const float4*)(xp);
    float4 xvb = *(const float4*)(xp + 4);
    float4 xvc = *(const float4*)(xp + 8);
    float4 xvd = *(const float4*)(xp + 12);
    float4 wd0 = *(const float4*)(wdp);
    float4 wd1 = *(const float4*)(wdp + 4);
    float4 wb0 = *(const float4*)(wbp);
    float4 wb1 = *(const float4*)(wbp + 4);

    for (int k0 = 0; k0 < CIN; k0 += BK) {
        __syncthreads();   // previous tile's compute done
        xs[lk +  0][lm] = xva.x;  xs[lk +  1][lm] = xva.y;
        xs[lk +  2][lm] = xva.z;  xs[lk +  3][lm] = xva.w;
        xs[lk +  4][lm] = xvb.x;  xs[lk +  5][lm] = xvb.y;
        xs[lk +  6][lm] = xvb.z;  xs[lk +  7][lm] = xvb.w;
        xs[lk +  8][lm] = xvc.x;  xs[lk +  9][lm] = xvc.y;
        xs[lk + 10][lm] = xvc.z;  xs[lk + 11][lm] = xvc.w;
        xs[lk + 12][lm] = xvd.x;  xs[lk + 13][lm] = xvd.y;
        xs[lk + 14][lm] = xvd.z;  xs[lk + 15][lm] = xvd.w;
        *(float4*)&wds[wr][wc]     = wd0;
        *(float4*)&wds[wr][wc + 4] = wd1;
        *(float4*)&wbs[wr][wc]     = wb0;
        *(float4*)&wbs[wr][wc + 4] = wb1;
        __syncthreads();

        // issue next tile's global loads (in flight during compute)
        const int kn = k0 + BK;
        if (kn < CIN) {
            xva = *(const float4*)(xp + kn);
            xvb = *(const float4*)(xp + kn + 4);
            xvc = *(const float4*)(xp + kn + 8);
            xvd = *(const float4*)(xp + kn + 12);
            wd0 = *(const float4*)(wdp + (size_t)kn * DD);
            wd1 = *(const float4*)(wdp + (size_t)kn * DD + 4);
            wb0 = *(const float4*)(wbp + (size_t)kn * DD);
            wb1 = *(const float4*)(wbp + (size_t)kn * DD + 4);
        }

#pragma unroll
        for (int kk = 0; kk < BK; ++kk) {
            float4 xa  = *(const float4*)&xs[kk][ty * 8];
            float4 xa2 = *(const float4*)&xs[kk][ty * 8 + 4];
            float4 d0  = *(const float4*)&wds[kk][tx * 4];
            float4 c0  = *(const float4*)&wbs[kk][tx * 4];
            float xr[8] = {xa.x, xa.y, xa.z, xa.w, xa2.x, xa2.y, xa2.z, xa2.w};
            float wd[4] = {d0.x, d0.y, d0.z, d0.w};
            float wb[4] = {c0.x, c0.y, c0.z, c0.w};
#pragma unroll
            for (int r = 0; r < 8; ++r) {
                const float xi = xr[r];
#pragma unroll
                for (int c = 0; c < 4; ++c) {
                    accd[r][c] = fmaf(xi, wd[c], accd[r][c]);
                    accb[r][c] = fmaf(xi, wb[c], accb[r][c]);
                }
            }
        }
    }

    // ---- epilogue ----
    const int nc0 = n0 + tx * 4;
    float4 bdq = *(const float4*)(bd + nc0);
    float4 bbq = *(const float4*)(bb + nc0);
    float4 alq = *(const float4*)(A_log + nc0);
    const float* bdv = (const float*)&bdq;
    const float* bbv = (const float*)&bbq;
    float Aq[4] = {expf(alq.x), expf(alq.y), expf(alq.z), expf(alq.w)};

#pragma unroll
    for (int r = 0; r < 8; ++r) {
        const int m = m0 + ty * 8 + r;
        float av[4], bv[4];
#pragma unroll
        for (int j = 0; j < 4; ++j) {
            float zd    = accd[r][j] + bdv[j];
            float delta = softplus_f(zd);
            float zb    = accb[r][j] + bbv[j];
            av[j] = expf(-delta * Aq[j]);
            bv[j] = delta * zb;
        }
        *(float4*)(a_out + (size_t)m * DD + nc0) = make_float4(av[0], av[1], av[2], av[3]);
        *(float4*)(b_out + (size_t)m * DD + nc0) = make_float4(bv[0], bv[1], bv[2], bv[3]);
    }
}

// ---- fused scan + LayerNorm (512 threads, 2 features/thread) ----
// Per output batch (2 lgkm-only barriers):
//   scan PF steps (spikes written inline, h stashed in regs)
//   pre-sum (sum, sumsq) per step -> trans[tid][0..15]   (pad 17: bank-free)
//   PREFETCH next batch (global loads stay in flight across both barriers)
//   bar1 -> 512-thread column sum (rows i2*32+rs: conflict-free, 17 coprime
//           32) + 5-stage shfl over 32 partials -> red[16]
//   bar2 -> ALL threads read red[] (broadcast ds_reads) and compute mu/inv
//           redundantly (identical IEEE expr -> identical values), LN writes
// Hazards (2-barrier proof): trans reads (pre-bar2) vs next trans writes
// (post-bar2) OK; red write (pre-bar2) vs red reads (post-bar2) OK; red reads
// retired by the reader's own lgkmcnt(0) at next bar1, before the next red
// write (post next-bar1) OK.  All branches block-uniform.

#define PREFETCH(AV, BV)                                                  \
    {                                                                     \
        _Pragma("unroll")                                                 \
        for (int j = 0; j < PF; ++j) {                                    \
            AV[j] = *(const float2*)(ap + (size_t)j * DD);                \
            BV[j] = *(const float2*)(bp + (size_t)j * DD);                \
        }                                                                 \
        ap += (size_t)PF * DD; bp += (size_t)PF * DD;                     \
    }

#define WARM_SLOT(AV, BV)                                                 \
    {                                                                     \
        _Pragma("unroll")                                                 \
        for (int j = 0; j < PF; ++j) {                                    \
            h.x = fmaf(AV[j].x, h.x, BV[j].x);                            \
            h.y = fmaf(AV[j].y, h.y, BV[j].y);                            \
            h.x = ((h.x - th.x) > 0.f) ? 0.f : h.x;                       \
            h.y = ((h.y - th.y) > 0.f) ? 0.f : h.y;                       \
        }                                                                 \
    }

#define OUT_SLOT(AV, BV, PFOK)                                            \
    {                                                                     \
        float2 hj[PF];                                                    \
        _Pragma("unroll")                                                 \
        for (int j = 0; j < PF; ++j) {                                    \
            h.x = fmaf(AV[j].x, h.x, BV[j].x);                            \
            h.y = fmaf(AV[j].y, h.y, BV[j].y);                            \
            const bool kx = (h.x - th.x) > 0.f;                           \
            const bool ky = (h.y - th.y) > 0.f;                           \
            *(float2*)(sp + (size_t)j * DD) =                             \
                make_float2(kx ? 1.f : 0.f, ky ? 1.f : 0.f);              \
            h.x = kx ? 0.f : h.x;                                         \
            h.y = ky ? 0.f : h.y;                                         \
            hj[j] = h;                                                    \
        }                                                                 \
        sp += (size_t)PF * DD;                                            \
        _Pragma("unroll")                                                 \
        for (int j = 0; j < PF; ++j) {                                    \
            trans[tid][j]      = hj[j].x + hj[j].y;                       \
            trans[tid][j + PF] = fmaf(hj[j].x, hj[j].x,                   \
                                      hj[j].y * hj[j].y);                 \
        }                                                                 \
        if (PFOK) PREFETCH(AV, BV)                                        \
        lgkm_bar();                                                       \
        {                                                                 \
            float p = 0.f;                                                \
            _Pragma("unroll")                                             \
            for (int i2 = 0; i2 < 16; ++i2)                               \
                p += trans[i2 * 32 + rs][rq];                             \
            p += __shfl_down(p, 16);                                      \
            p += __shfl_down(p, 8);                                       \
            p += __shfl_down(p, 4);                                       \
            p += __shfl_down(p, 2);                                       \
            p += __shfl_down(p, 1);                                       \
            if (rs == 0) red[rq] = p;                                     \
        }                                                                 \
        lgkm_bar();                                                       \
        float mu_[PF], inv_[PF];                                          \
        _Pragma("unroll")                                                 \
        for (int j = 0; j < PF; ++j) {                                    \
            const float mu  = red[j] * (1.0f / DD);                       \
            const float var =                                             \
                fmaxf(red[j + PF] * (1.0f / DD) - mu * mu, 0.f);          \
            mu_[j]  = mu;                                                 \
            inv_[j] = 1.0f / sqrtf(var + 1e-5f);                          \
        }                                                                 \
        _Pragma("unroll")                                                 \
        for (int j = 0; j < PF; ++j) {                                    \
            float2 o;                                                     \
            o.x = (hj[j].x - mu_[j]) * inv_[j] * g.x + be.x;              \
            o.y = (hj[j].y - mu_[j]) * inv_[j] * g.y + be.y;              \
            *(float2*)(op + (size_t)j * DD) = o;                          \
        }                                                                 \
        op += (size_t)PF * DD;                                            \
    }

__global__ __launch_bounds__(512) void k23_scan_ln(
    const float* __restrict__ a,      // [BB, TT, DD]
    const float* __restrict__ b,      // [BB, TT, DD]
    const float* __restrict__ thr,    // [DD]
    const float* __restrict__ gamma,  // [DD]
    const float* __restrict__ beta,   // [DD]
    float* __restrict__ out,          // [BB, TT, DD]
    float* __restrict__ spikes)       // [BB, TT, DD]
{
    const int tid   = threadIdx.x;     // 0..511 — two features per thread
    const int d0    = tid * 2;
    const int chunk = blockIdx.x;      // 0..31
    const int batch = blockIdx.y;      // 0..7
    const int rq    = tid >> 5;        // 0..15: quantity (0..7 sum, 8..15 ssq)
    const int rs    = tid & 31;        // 0..31: summer index within quantity

    const float2 th = *(const float2*)(thr + d0);
    const float2 g  = *(const float2*)(gamma + d0);
    const float2 be = *(const float2*)(beta + d0);

    const int t0    = chunk * CLEN;
    const int nwarm = (t0 < WARM) ? t0 : WARM;   // 0 or 64; chunks 0-1 exact
    const int tw    = t0 - nwarm;
    const int nwb   = nwarm / PF;                // 0 or 8
    const int ntot  = nwb + CLEN / PF;           // 8 or 16 (even)

    const size_t rowbase = (size_t)batch * TT * DD + d0;
    const float* ap = a + rowbase + (size_t)tw * DD;
    const float* bp = b + rowbase + (size_t)tw * DD;
    float* op = out    + rowbase + (size_t)t0 * DD;
    float* sp = spikes + rowbase + (size_t)t0 * DD;

    __shared__ float trans[512][17];   // 34816 B, pad 17 -> bank-conflict-free
    __shared__ float red[2 * PF];

    float2 a0[PF], b0[PF], a1[PF], b1[PF];
    PREFETCH(a0, b0)
    PREFETCH(a1, b1)

    float2 h = make_float2(0.f, 0.f);
    for (int i = 0; i < ntot; i += 2) {
        if (i >= nwb) OUT_SLOT(a0, b0, i + 2 < ntot)
        else { WARM_SLOT(a0, b0) PREFETCH(a0, b0) }

        if (i + 1 >= nwb) OUT_SLOT(a1, b1, i + 3 < ntot)
        else { WARM_SLOT(a1, b1) PREFETCH(a1, b1) }
    }
}

extern "C" void kernel_launch(void* const* d_in, const int* in_sizes, int n_in,
                              void* d_out, int out_size, void* d_ws, size_t ws_size,
                              hipStream_t stream) {
    const float* x     = (const float*)d_in[0];
    const float* Wd    = (const float*)d_in[1];
    const float* bd    = (const float*)d_in[2];
    const float* Wb    = (const float*)d_in[3];
    const float* bb    = (const float*)d_in[4];
    const float* A_log = (const float*)d_in[5];
    const float* thr   = (const float*)d_in[6];
    const float* gamma = (const float*)d_in[7];
    const float* beta  = (const float*)d_in[8];

    float* out    = (float*)d_out;                    // [MM, DD] LN output
    float* spikes = out + (size_t)MM * DD;            // [MM, DD]
    float* a_ws   = (float*)d_ws;                     // [MM, DD]
    float* b_ws   = a_ws + (size_t)MM * DD;           // [MM, DD]

    dim3 g1(DD / BN, MM / BM);                        // (16, 128)
    k1_gemm_act<<<g1, 256, 0, stream>>>(x, Wd, Wb, bd, bb, A_log, a_ws, b_ws);

    dim3 g2(NCHUNK, BB);                              // (32, 8) = 256 blocks, 1/CU
    k23_scan_ln<<<g2, 512, 0, stream>>>(a_ws, b_ws, thr, gamma, beta, out, spikes);
}

// Round 10
// 638.453 us; speedup vs baseline: 1.0512x; 1.0180x over previous
//
#include <hip/hip_runtime.h>
#include <math.h>

// Problem dims (fixed by reference)
#define BB   8
#define TT   2048
#define CIN  512
#define DD   1024
#define MM   (BB * TT)     // 16384 rows for the GEMMs

// K1 GEMM tiling: 128x64 block tile, 256 threads, 8x4 dual micro-tile.
// K1 IS FROZEN.  Four structural probes all regressed:
//  R1: 128-acc microtile -> spill (VGPR cap 128, WRITE_SIZE 4x)
//  R2: explicit LDS double-buffer -> VGPR 180, occupancy halved, 695us
//  R7: lgkm-only barriers -> vmcnt wait moves to staging ds_write, 502us
//  R9: BK=32 -> w-staging 8-way bank conflict (4.19M->8.39M), 538us
// The round-0 2-barrier single-buffer BK=16 loop at 92 VGPR = 474-483us.
constexpr int BM = 128;
constexpr int BN = 64;
constexpr int BK = 16;

// K2+K3 fused scan+LN: 2 features/thread (float2), h_post never hits HBM.
// R7 LESSON: lgkm-only barriers help k23 (loads consumed a batch later stay
// in flight).  R8 LESSON: time ~ total bytes at ~2.8TB/s duty ceiling ->
// NCHUNK=32 minimizes warm amplification (1.97x).
// R10: the excess over the 63us traffic floor is the reduce critical section
// (2 barriers + shfl tree per 8-step batch, serialized at 1 block/CU).
// Fuse the reduce of TWO consecutive batches into one barrier pair ->
// 1 barrier/batch; both slots' prefetches issue before the reduce.
// trans[512][33] = 67.6KB (1 block/CU, grid=256 -> fine); 32 quantities x
// 16 summers; writes conflict-free (33 = 1 mod 32), reads <=2-way.
// WARM=64: contamination = h_start*exp(-sum delta*A); sum of 64
// softplus(N(0,1)) ~ N(45,6.4), P(sum<9) ~ 5.6 sigma -> error <= ~1e-4.
// nwb even (0 or 8) and ntot even -> pairs are homogeneous (warm or out).
#define NCHUNK 32
#define CLEN   (TT / NCHUNK)   // 64
#define WARM   64
#define PF     8

// LDS-only barrier: waits LDS ops, leaves global loads/stores in flight.
// Use ONLY where loaded registers are not consumed immediately after the
// barrier (k23 yes, k1 no — round-7 lesson).
__device__ __forceinline__ void lgkm_bar() {
    asm volatile("s_waitcnt lgkmcnt(0)" ::: "memory");
    __builtin_amdgcn_s_barrier();
}

// softplus(z) = logaddexp(z, 0) — matches jax.nn.softplus / np.logaddexp
__device__ __forceinline__ float softplus_f(float z) {
    return fmaxf(z, 0.f) + log1pf(expf(-fabsf(z)));
}

// K1: fused dual GEMM  zd = x@Wd, zb = x@Wb  (+bias)  →  a_step, b_step
__global__ __launch_bounds__(256) void k1_gemm_act(
    const float* __restrict__ x,      // [MM, CIN]
    const float* __restrict__ Wd,     // [CIN, DD]
    const float* __restrict__ Wb,     // [CIN, DD]
    const float* __restrict__ bd,     // [DD]
    const float* __restrict__ bb,     // [DD]
    const float* __restrict__ A_log,  // [DD]
    float* __restrict__ a_out,        // [MM, DD]
    float* __restrict__ b_out)        // [MM, DD]
{
    // xs transposed: xs[k][m] -> x-fragments are b128 reads; scatter stores 2-way (free).
    __shared__ float xs[BK][BM + 4];
    __shared__ float wds[BK][BN];
    __shared__ float wbs[BK][BN];

    const int tid = threadIdx.x;
    const int n0  = blockIdx.x * BN;
    const int m0  = blockIdx.y * BM;
    const int tx  = tid & 15;          // col group: 4 cols each
    const int ty  = tid >> 4;          // row group: 8 rows each

    // staging indices
    const int lm = tid >> 1;           // 0..127  x row
    const int lk = (tid & 1) * 8;      // 0 or 8  (two float4 = 8 k)
    const int wr = tid >> 4;           // 0..15   w row
    const int wc = (tid & 15) * 4;     // 0..60   w col

    float accd[8][4], accb[8][4];
#pragma unroll
    for (int r = 0; r < 8; ++r)
#pragma unroll
        for (int c = 0; c < 4; ++c) { accd[r][c] = 0.f; accb[r][c] = 0.f; }

    // ---- preload tile 0 into registers ----
    const float* xp  = x + (size_t)(m0 + lm) * CIN + lk;
    const float* wdp = Wd + (size_t)wr * DD + n0 + wc;
    const float* wbp = Wb + (size_t)wr * DD + n0 + wc;
    float4 xva = *(const float4*)(xp);
    float4 xvb = *(const float4*)(xp + 4);
    float4 wd0 = *(const float4*)(wdp);
    float4 wb0 = *(const float4*)(wbp);

    for (int k0 = 0; k0 < CIN; k0 += BK) {
        __syncthreads();   // previous tile's compute done
        xs[lk + 0][lm] = xva.x;  xs[lk + 1][lm] = xva.y;
        xs[lk + 2][lm] = xva.z;  xs[lk + 3][lm] = xva.w;
        xs[lk + 4][lm] = xvb.x;  xs[lk + 5][lm] = xvb.y;
        xs[lk + 6][lm] = xvb.z;  xs[lk + 7][lm] = xvb.w;
        *(float4*)&wds[wr][wc] = wd0;
        *(float4*)&wbs[wr][wc] = wb0;
        __syncthreads();

        // issue next tile's global loads (in flight during compute)
        const int kn = k0 + BK;
        if (kn < CIN) {
            xva = *(const float4*)(xp + kn);
            xvb = *(const float4*)(xp + kn + 4);
            wd0 = *(const float4*)(wdp + (size_t)kn * DD);
            wb0 = *(const float4*)(wbp + (size_t)kn * DD);
        }

#pragma unroll
        for (int kk = 0; kk < BK; ++kk) {
            float4 xa  = *(const float4*)&xs[kk][ty * 8];
            float4 xa2 = *(const float4*)&xs[kk][ty * 8 + 4];
            float4 d0  = *(const float4*)&wds[kk][tx * 4];
            float4 c0  = *(const float4*)&wbs[kk][tx * 4];
            float xr[8] = {xa.x, xa.y, xa.z, xa.w, xa2.x, xa2.y, xa2.z, xa2.w};
            float wd[4] = {d0.x, d0.y, d0.z, d0.w};
            float wb[4] = {c0.x, c0.y, c0.z, c0.w};
#pragma unroll
            for (int r = 0; r < 8; ++r) {
                const float xi = xr[r];
#pragma unroll
                for (int c = 0; c < 4; ++c) {
                    accd[r][c] = fmaf(xi, wd[c], accd[r][c]);
                    accb[r][c] = fmaf(xi, wb[c], accb[r][c]);
                }
            }
        }
    }

    // ---- epilogue ----
    const int nc0 = n0 + tx * 4;
    float4 bdq = *(const float4*)(bd + nc0);
    float4 bbq = *(const float4*)(bb + nc0);
    float4 alq = *(const float4*)(A_log + nc0);
    const float* bdv = (const float*)&bdq;
    const float* bbv = (const float*)&bbq;
    float Aq[4] = {expf(alq.x), expf(alq.y), expf(alq.z), expf(alq.w)};

#pragma unroll
    for (int r = 0; r < 8; ++r) {
        const int m = m0 + ty * 8 + r;
        float av[4], bv[4];
#pragma unroll
        for (int j = 0; j < 4; ++j) {
            float zd    = accd[r][j] + bdv[j];
            float delta = softplus_f(zd);
            float zb    = accb[r][j] + bbv[j];
            av[j] = expf(-delta * Aq[j]);
            bv[j] = delta * zb;
        }
        *(float4*)(a_out + (size_t)m * DD + nc0) = make_float4(av[0], av[1], av[2], av[3]);
        *(float4*)(b_out + (size_t)m * DD + nc0) = make_float4(bv[0], bv[1], bv[2], bv[3]);
    }
}

// ---- fused scan + LayerNorm (512 threads, 2 features/thread) ----
// Per output PAIR (2 batches, 2 lgkm-only barriers = 1 barrier/batch):
//   scan slot0 (spikes inline, h stash hj0) -> trans cols 0..15
//   prefetch next-pair slot0
//   scan slot1 (hj1) -> trans cols 16..31
//   prefetch next-pair slot1
//   bar1 -> column sum: 16 summers x 32 rows per quantity (32 quantities),
//           4-stage shfl over 16 partials -> red[32]
//   bar2 -> all threads read red[] (broadcast), mu/inv computed redundantly-
//           identically, LN writes for both batches
// Hazards: trans writes pre-bar1 / reads bar1..bar2 / next writes post-bar2 OK;
// red write bar1..bar2 / reads post-bar2, retired by reader's lgkmcnt(0) at
// next bar1, before next red write (also post-next-bar1) OK.  All branches
// block-uniform.

#define PREFETCH(AV, BV)                                                  \
    {                                                                     \
        _Pragma("unroll")                                                 \
        for (int j = 0; j < PF; ++j) {                                    \
            AV[j] = *(const float2*)(ap + (size_t)j * DD);                \
            BV[j] = *(const float2*)(bp + (size_t)j * DD);                \
        }                                                                 \
        ap += (size_t)PF * DD; bp += (size_t)PF * DD;                     \
    }

#define WARM_SLOT(AV, BV)                                                 \
    {                                                                     \
        _Pragma("unroll")                                                 \
        for (int j = 0; j < PF; ++j) {                                    \
            h.x = fmaf(AV[j].x, h.x, BV[j].x);                            \
            h.y = fmaf(AV[j].y, h.y, BV[j].y);                            \
            h.x = ((h.x - th.x) > 0.f) ? 0.f : h.x;                       \
            h.y = ((h.y - th.y) > 0.f) ? 0.f : h.y;                       \
        }                                                                 \
    }

// scan one slot into HJ, write spikes, write trans columns [C0..C0+15]
#define SCAN_SLOT(AV, BV, HJ, C0)                                         \
    {                                                                     \
        _Pragma("unroll")                                                 \
        for (int j = 0; j < PF; ++j) {                                    \
            h.x = fmaf(AV[j].x, h.x, BV[j].x);                            \
            h.y = fmaf(AV[j].y, h.y, BV[j].y);                            \
            const bool kx = (h.x - th.x) > 0.f;                           \
            const bool ky = (h.y - th.y) > 0.f;                           \
            *(float2*)(sp + (size_t)j * DD) =                             \
                make_float2(kx ? 1.f : 0.f, ky ? 1.f : 0.f);              \
            h.x = kx ? 0.f : h.x;                                         \
            h.y = ky ? 0.f : h.y;                                         \
            HJ[j] = h;                                                    \
        }                                                                 \
        sp += (size_t)PF * DD;                                            \
        _Pragma("unroll")                                                 \
        for (int j = 0; j < PF; ++j) {                                    \
            trans[tid][(C0) + j]      = HJ[j].x + HJ[j].y;                \
            trans[tid][(C0) + j + PF] = fmaf(HJ[j].x, HJ[j].x,            \
                                             HJ[j].y * HJ[j].y);          \
        }                                                                 \
    }

// LN-write one batch from HJ using red[RB..RB+15]
#define LN_WRITE(HJ, RB)                                                  \
    {                                                                     \
        _Pragma("unroll")                                                 \
        for (int j = 0; j < PF; ++j) {                                    \
            const float mu  = red[(RB) + j] * (1.0f / DD);                \
            const float var =                                             \
                fmaxf(red[(RB) + j + PF] * (1.0f / DD) - mu * mu, 0.f);   \
            const float inv = 1.0f / sqrtf(var + 1e-5f);                  \
            float2 o;                                                     \
            o.x = (HJ[j].x - mu) * inv * g.x + be.x;                      \
            o.y = (HJ[j].y - mu) * inv * g.y + be.y;                      \
            *(float2*)(op + (size_t)j * DD) = o;                          \
        }                                                                 \
        op += (size_t)PF * DD;                                            \
    }

#define OUT_PAIR(PFOK)                                                    \
    {                                                                     \
        float2 hj0[PF], hj1[PF];                                          \
        SCAN_SLOT(a0, b0, hj0, 0)                                         \
        if (PFOK) PREFETCH(a0, b0)                                        \
        SCAN_SLOT(a1, b1, hj1, 16)                                        \
        if (PFOK) PREFETCH(a1, b1)                                        \
        lgkm_bar();                                                       \
        {                                                                 \
            float p = 0.f;                                                \
            _Pragma("unroll")                                             \
            for (int i2 = 0; i2 < 32; ++i2)                               \
                p += trans[i2 * 16 + rs][rq];                             \
            p += __shfl_down(p, 8);                                       \
            p += __shfl_down(p, 4);                                       \
            p += __shfl_down(p, 2);                                       \
            p += __shfl_down(p, 1);                                       \
            if (rs == 0) red[rq] = p;                                     \
        }                                                                 \
        lgkm_bar();                                                       \
        LN_WRITE(hj0, 0)                                                  \
        LN_WRITE(hj1, 16)                                                 \
    }

__global__ __launch_bounds__(512) void k23_scan_ln(
    const float* __restrict__ a,      // [BB, TT, DD]
    const float* __restrict__ b,      // [BB, TT, DD]
    const float* __restrict__ thr,    // [DD]
    const float* __restrict__ gamma,  // [DD]
    const float* __restrict__ beta,   // [DD]
    float* __restrict__ out,          // [BB, TT, DD]
    float* __restrict__ spikes)       // [BB, TT, DD]
{
    const int tid   = threadIdx.x;     // 0..511 — two features per thread
    const int d0    = tid * 2;
    const int chunk = blockIdx.x;      // 0..31
    const int batch = blockIdx.y;      // 0..7
    const int rq    = tid >> 4;        // 0..31: quantity (pair-fused layout)
    const int rs    = tid & 15;        // 0..15: summer index within quantity

    const float2 th = *(const float2*)(thr + d0);
    const float2 g  = *(const float2*)(gamma + d0);
    const float2 be = *(const float2*)(beta + d0);

    const int t0    = chunk * CLEN;
    const int nwarm = (t0 < WARM) ? t0 : WARM;   // 0 or 64; chunks 0-1 exact
    const int tw    = t0 - nwarm;
    const int nwb   = nwarm / PF;                // 0 or 8 (even)
    const int ntot  = nwb + CLEN / PF;           // 8 or 16 (even)

    const size_t rowbase = (size_t)batch * TT * DD + d0;
    const float* ap = a + rowbase + (size_t)tw * DD;
    const float* bp = b + rowbase + (size_t)tw * DD;
    float* op = out    + rowbase + (size_t)t0 * DD;
    float* sp = spikes + rowbase + (size_t)t0 * DD;

    __shared__ float trans[512][33];   // 67584 B; 33 = 1 mod 32 -> writes
                                       // conflict-free, reads <=2-way
    __shared__ float red[32];

    float2 a0[PF], b0[PF], a1[PF], b1[PF];
    PREFETCH(a0, b0)
    PREFETCH(a1, b1)

    float2 h = make_float2(0.f, 0.f);
    for (int i = 0; i < ntot; i += 2) {
        if (i >= nwb) {
            OUT_PAIR(i + 2 < ntot)
        } else {
            WARM_SLOT(a0, b0) PREFETCH(a0, b0)
            WARM_SLOT(a1, b1) PREFETCH(a1, b1)
        }
    }
}

extern "C" void kernel_launch(void* const* d_in, const int* in_sizes, int n_in,
                              void* d_out, int out_size, void* d_ws, size_t ws_size,
                              hipStream_t stream) {
    const float* x     = (const float*)d_in[0];
    const float* Wd    = (const float*)d_in[1];
    const float* bd    = (const float*)d_in[2];
    const float* Wb    = (const float*)d_in[3];
    const float* bb    = (const float*)d_in[4];
    const float* A_log = (const float*)d_in[5];
    const float* thr   = (const float*)d_in[6];
    const float* gamma = (const float*)d_in[7];
    const float* beta  = (const float*)d_in[8];

    float* out    = (float*)d_out;                    // [MM, DD] LN output
    float* spikes = out + (size_t)MM * DD;            // [MM, DD]
    float* a_ws   = (float*)d_ws;                     // [MM, DD]
    float* b_ws   = a_ws + (size_t)MM * DD;           // [MM, DD]

    dim3 g1(DD / BN, MM / BM);                        // (16, 128)
    k1_gemm_act<<<g1, 256, 0, stream>>>(x, Wd, Wb, bd, bb, A_log, a_ws, b_ws);

    dim3 g2(NCHUNK, BB);                              // (32, 8) = 256 blocks, 1/CU
    k23_scan_ln<<<g2, 512, 0, stream>>>(a_ws, b_ws, thr, gamma, beta, out, spikes);
}

// Round 11
// 635.040 us; speedup vs baseline: 1.0569x; 1.0054x over previous
//
#include <hip/hip_runtime.h>
#include <math.h>

// Problem dims (fixed by reference)
#define BB   8
#define TT   2048
#define CIN  512
#define DD   1024
#define MM   (BB * TT)     // 16384 rows for the GEMMs

// K1 GEMM tiling: 128x64 block tile, 256 threads, 8x4 dual micro-tile.
// K1 FMA LOOP IS FROZEN.  Four structural probes all regressed:
//  R1: 128-acc microtile -> spill (VGPR cap 128, WRITE_SIZE 4x)
//  R2: explicit LDS double-buffer -> VGPR 180, occupancy halved, 695us
//  R7: lgkm-only barriers -> vmcnt wait moves to staging ds_write, 502us
//  R9: BK=32 -> w-staging 8-way bank conflict (4.19M->8.39M), 538us
// Round-0 2-barrier single-buffer BK=16 loop at 92 VGPR = 474-486us.
// R11: epilogue now writes an INTERLEAVED workspace ab_ws[m][2*DD]:
// quad f=4t holds (a[2t], a[2t+1], b[2t], b[2t+1]) so k23 loads ONE float4
// per step instead of two float2s from arrays 64MB apart.  Same 131MB, still
// fully coalesced (two adjacent float4 stores per thread).
constexpr int BM = 128;
constexpr int BN = 64;
constexpr int BK = 16;

// K2+K3 fused scan+LN: 2 features/thread, h_post never hits HBM.
// R7 LESSON: lgkm-only barriers help k23 (loads consumed a batch later stay
// in flight across barriers).  R8 LESSON: time ~ total bytes at the observed
// duty ceiling -> NCHUNK=32 minimizes warm amplification (1.97x).
// R10 LESSON: pair-fused reduce (1 barrier/batch but 32-deep serial read
// chain + 67KB trans) was WORSE (154 vs 143) than the R7 reduce — the reduce
// dependency chain, not barrier count, is what matters.  R7 reduce restored:
// trans[512][17], 16-row read chain, 5-stage shfl, 2 lgkm bars/batch.
// R11: loads are float4 (interleaved ab) — half the load instructions.
// WARM=64: contamination = h_start*exp(-sum delta*A); sum of 64
// softplus(N(0,1)) ~ N(45,6.4), P(sum<9) ~ 5.6 sigma -> error <= ~1e-4.
#define NCHUNK 32
#define CLEN   (TT / NCHUNK)   // 64
#define WARM   64
#define PF     8

// LDS-only barrier: waits LDS ops, leaves global loads/stores in flight.
// Use ONLY where loaded registers are not consumed immediately after the
// barrier (k23 yes, k1 no — round-7 lesson).
__device__ __forceinline__ void lgkm_bar() {
    asm volatile("s_waitcnt lgkmcnt(0)" ::: "memory");
    __builtin_amdgcn_s_barrier();
}

// softplus(z) = logaddexp(z, 0) — matches jax.nn.softplus / np.logaddexp
__device__ __forceinline__ float softplus_f(float z) {
    return fmaxf(z, 0.f) + log1pf(expf(-fabsf(z)));
}

// K1: fused dual GEMM  zd = x@Wd, zb = x@Wb  (+bias)  →  interleaved (a,b)
__global__ __launch_bounds__(256) void k1_gemm_act(
    const float* __restrict__ x,      // [MM, CIN]
    const float* __restrict__ Wd,     // [CIN, DD]
    const float* __restrict__ Wb,     // [CIN, DD]
    const float* __restrict__ bd,     // [DD]
    const float* __restrict__ bb,     // [DD]
    const float* __restrict__ A_log,  // [DD]
    float* __restrict__ ab_out)       // [MM, 2*DD] interleaved quads
{
    // xs transposed: xs[k][m] -> x-fragments are b128 reads; scatter stores 2-way (free).
    __shared__ float xs[BK][BM + 4];
    __shared__ float wds[BK][BN];
    __shared__ float wbs[BK][BN];

    const int tid = threadIdx.x;
    const int n0  = blockIdx.x * BN;
    const int m0  = blockIdx.y * BM;
    const int tx  = tid & 15;          // col group: 4 cols each
    const int ty  = tid >> 4;          // row group: 8 rows each

    // staging indices
    const int lm = tid >> 1;           // 0..127  x row
    const int lk = (tid & 1) * 8;      // 0 or 8  (two float4 = 8 k)
    const int wr = tid >> 4;           // 0..15   w row
    const int wc = (tid & 15) * 4;     // 0..60   w col

    float accd[8][4], accb[8][4];
#pragma unroll
    for (int r = 0; r < 8; ++r)
#pragma unroll
        for (int c = 0; c < 4; ++c) { accd[r][c] = 0.f; accb[r][c] = 0.f; }

    // ---- preload tile 0 into registers ----
    const float* xp  = x + (size_t)(m0 + lm) * CIN + lk;
    const float* wdp = Wd + (size_t)wr * DD + n0 + wc;
    const float* wbp = Wb + (size_t)wr * DD + n0 + wc;
    float4 xva = *(const float4*)(xp);
    float4 xvb = *(const float4*)(xp + 4);
    float4 wd0 = *(const float4*)(wdp);
    float4 wb0 = *(const float4*)(wbp);

    for (int k0 = 0; k0 < CIN; k0 += BK) {
        __syncthreads();   // previous tile's compute done
        xs[lk + 0][lm] = xva.x;  xs[lk + 1][lm] = xva.y;
        xs[lk + 2][lm] = xva.z;  xs[lk + 3][lm] = xva.w;
        xs[lk + 4][lm] = xvb.x;  xs[lk + 5][lm] = xvb.y;
        xs[lk + 6][lm] = xvb.z;  xs[lk + 7][lm] = xvb.w;
        *(float4*)&wds[wr][wc] = wd0;
        *(float4*)&wbs[wr][wc] = wb0;
        __syncthreads();

        // issue next tile's global loads (in flight during compute)
        const int kn = k0 + BK;
        if (kn < CIN) {
            xva = *(const float4*)(xp + kn);
            xvb = *(const float4*)(xp + kn + 4);
            wd0 = *(const float4*)(wdp + (size_t)kn * DD);
            wb0 = *(const float4*)(wbp + (size_t)kn * DD);
        }

#pragma unroll
        for (int kk = 0; kk < BK; ++kk) {
            float4 xa  = *(const float4*)&xs[kk][ty * 8];
            float4 xa2 = *(const float4*)&xs[kk][ty * 8 + 4];
            float4 d0  = *(const float4*)&wds[kk][tx * 4];
            float4 c0  = *(const float4*)&wbs[kk][tx * 4];
            float xr[8] = {xa.x, xa.y, xa.z, xa.w, xa2.x, xa2.y, xa2.z, xa2.w};
            float wd[4] = {d0.x, d0.y, d0.z, d0.w};
            float wb[4] = {c0.x, c0.y, c0.z, c0.w};
#pragma unroll
            for (int r = 0; r < 8; ++r) {
                const float xi = xr[r];
#pragma unroll
                for (int c = 0; c < 4; ++c) {
                    accd[r][c] = fmaf(xi, wd[c], accd[r][c]);
                    accb[r][c] = fmaf(xi, wb[c], accb[r][c]);
                }
            }
        }
    }

    // ---- epilogue: interleaved quads (a0,a1,b0,b1)(a2,a3,b2,b3) ----
    const int nc0 = n0 + tx * 4;
    float4 bdq = *(const float4*)(bd + nc0);
    float4 bbq = *(const float4*)(bb + nc0);
    float4 alq = *(const float4*)(A_log + nc0);
    const float* bdv = (const float*)&bdq;
    const float* bbv = (const float*)&bbq;
    float Aq[4] = {expf(alq.x), expf(alq.y), expf(alq.z), expf(alq.w)};

#pragma unroll
    for (int r = 0; r < 8; ++r) {
        const int m = m0 + ty * 8 + r;
        float av[4], bv[4];
#pragma unroll
        for (int j = 0; j < 4; ++j) {
            float zd    = accd[r][j] + bdv[j];
            float delta = softplus_f(zd);
            float zb    = accb[r][j] + bbv[j];
            av[j] = expf(-delta * Aq[j]);
            bv[j] = delta * zb;
        }
        float* abp = ab_out + (size_t)m * (2 * DD) + 2 * nc0;
        *(float4*)(abp)     = make_float4(av[0], av[1], bv[0], bv[1]);
        *(float4*)(abp + 4) = make_float4(av[2], av[3], bv[2], bv[3]);
    }
}

// ---- fused scan + LayerNorm (512 threads, 2 features/thread) ----
// Per output batch (R7 reduce, 2 lgkm-only barriers):
//   scan PF steps from float4 ab quads (spikes inline, h stashed in regs)
//   pre-sum (sum, sumsq) per step -> trans[tid][0..15]   (pad 17: bank-free)
//   PREFETCH next batch (global loads stay in flight across both barriers)
//   bar1 -> 512-thread column sum (16 rows/thread at i2*32+rs) + 5-stage shfl
//           over 32 partials -> red[16]
//   bar2 -> all threads read red[] (broadcast) and compute mu/inv
//           redundantly-identically, LN writes
// Hazards: trans reads (pre-bar2) vs next trans writes (post-bar2) OK; red
// write (pre-bar2) vs reads (post-bar2) OK; red reads retired by reader's
// lgkmcnt(0) at next bar1, before next red write OK.  Branches block-uniform.

#define PREFETCH(ABV)                                                     \
    {                                                                     \
        _Pragma("unroll")                                                 \
        for (int j = 0; j < PF; ++j)                                      \
            ABV[j] = *(const float4*)(abp + (size_t)j * (2 * DD));        \
        abp += (size_t)PF * (2 * DD);                                     \
    }

#define WARM_SLOT(ABV)                                                    \
    {                                                                     \
        _Pragma("unroll")                                                 \
        for (int j = 0; j < PF; ++j) {                                    \
            h.x = fmaf(ABV[j].x, h.x, ABV[j].z);                          \
            h.y = fmaf(ABV[j].y, h.y, ABV[j].w);                          \
            h.x = ((h.x - th.x) > 0.f) ? 0.f : h.x;                       \
            h.y = ((h.y - th.y) > 0.f) ? 0.f : h.y;                       \
        }                                                                 \
    }

#define OUT_SLOT(ABV, PFOK)                                               \
    {                                                                     \
        float2 hj[PF];                                                    \
        _Pragma("unroll")                                                 \
        for (int j = 0; j < PF; ++j) {                                    \
            h.x = fmaf(ABV[j].x, h.x, ABV[j].z);                          \
            h.y = fmaf(ABV[j].y, h.y, ABV[j].w);                          \
            const bool kx = (h.x - th.x) > 0.f;                           \
            const bool ky = (h.y - th.y) > 0.f;                           \
            *(float2*)(sp + (size_t)j * DD) =                             \
                make_float2(kx ? 1.f : 0.f, ky ? 1.f : 0.f);              \
            h.x = kx ? 0.f : h.x;                                         \
            h.y = ky ? 0.f : h.y;                                         \
            hj[j] = h;                                                    \
        }                                                                 \
        sp += (size_t)PF * DD;                                            \
        _Pragma("unroll")                                                 \
        for (int j = 0; j < PF; ++j) {                                    \
            trans[tid][j]      = hj[j].x + hj[j].y;                       \
            trans[tid][j + PF] = fmaf(hj[j].x, hj[j].x,                   \
                                      hj[j].y * hj[j].y);                 \
        }                                                                 \
        if (PFOK) PREFETCH(ABV)                                           \
        lgkm_bar();                                                       \
        {                                                                 \
            float p = 0.f;                                                \
            _Pragma("unroll")                                             \
            for (int i2 = 0; i2 < 16; ++i2)                               \
                p += trans[i2 * 32 + rs][rq];                             \
            p += __shfl_down(p, 16);                                      \
            p += __shfl_down(p, 8);                                       \
            p += __shfl_down(p, 4);                                       \
            p += __shfl_down(p, 2);                                       \
            p += __shfl_down(p, 1);                                       \
            if (rs == 0) red[rq] = p;                                     \
        }                                                                 \
        lgkm_bar();                                                       \
        float mu_[PF], inv_[PF];                                          \
        _Pragma("unroll")                                                 \
        for (int j = 0; j < PF; ++j) {                                    \
            const float mu  = red[j] * (1.0f / DD);                       \
            const float var =                                             \
                fmaxf(red[j + PF] * (1.0f / DD) - mu * mu, 0.f);          \
            mu_[j]  = mu;                                                 \
            inv_[j] = 1.0f / sqrtf(var + 1e-5f);                          \
        }                                                                 \
        _Pragma("unroll")                                                 \
        for (int j = 0; j < PF; ++j) {                                    \
            float2 o;                                                     \
            o.x = (hj[j].x - mu_[j]) * inv_[j] * g.x + be.x;              \
            o.y = (hj[j].y - mu_[j]) * inv_[j] * g.y + be.y;              \
            *(float2*)(op + (size_t)j * DD) = o;                          \
        }                                                                 \
        op += (size_t)PF * DD;                                            \
    }

__global__ __launch_bounds__(512) void k23_scan_ln(
    const float* __restrict__ ab,     // [BB, TT, 2*DD] interleaved quads
    const float* __restrict__ thr,    // [DD]
    const float* __restrict__ gamma,  // [DD]
    const float* __restrict__ beta,   // [DD]
    float* __restrict__ out,          // [BB, TT, DD]
    float* __restrict__ spikes)       // [BB, TT, DD]
{
    const int tid   = threadIdx.x;     // 0..511 — two features per thread
    const int d0    = tid * 2;
    const int chunk = blockIdx.x;      // 0..31
    const int batch = blockIdx.y;      // 0..7
    const int rq    = tid >> 5;        // 0..15: quantity (0..7 sum, 8..15 ssq)
    const int rs    = tid & 31;        // 0..31: summer index within quantity

    const float2 th = *(const float2*)(thr + d0);
    const float2 g  = *(const float2*)(gamma + d0);
    const float2 be = *(const float2*)(beta + d0);

    const int t0    = chunk * CLEN;
    const int nwarm = (t0 < WARM) ? t0 : WARM;   // 0 or 64; chunks 0-1 exact
    const int tw    = t0 - nwarm;
    const int nwb   = nwarm / PF;                // 0 or 8
    const int ntot  = nwb + CLEN / PF;           // 8 or 16 (even)

    const float* abp = ab + (size_t)batch * TT * (2 * DD)
                          + (size_t)tw * (2 * DD) + 4 * tid;
    const size_t rowbase = (size_t)batch * TT * DD + d0;
    float* op = out    + rowbase + (size_t)t0 * DD;
    float* sp = spikes + rowbase + (size_t)t0 * DD;

    __shared__ float trans[512][17];   // 34816 B, pad 17 -> bank-conflict-free
    __shared__ float red[2 * PF];

    float4 ab0[PF], ab1[PF];
    PREFETCH(ab0)
    PREFETCH(ab1)

    float2 h = make_float2(0.f, 0.f);
    for (int i = 0; i < ntot; i += 2) {
        if (i >= nwb) OUT_SLOT(ab0, i + 2 < ntot)
        else { WARM_SLOT(ab0) PREFETCH(ab0) }

        if (i + 1 >= nwb) OUT_SLOT(ab1, i + 3 < ntot)
        else { WARM_SLOT(ab1) PREFETCH(ab1) }
    }
}

extern "C" void kernel_launch(void* const* d_in, const int* in_sizes, int n_in,
                              void* d_out, int out_size, void* d_ws, size_t ws_size,
                              hipStream_t stream) {
    const float* x     = (const float*)d_in[0];
    const float* Wd    = (const float*)d_in[1];
    const float* bd    = (const float*)d_in[2];
    const float* Wb    = (const float*)d_in[3];
    const float* bb    = (const float*)d_in[4];
    const float* A_log = (const float*)d_in[5];
    const float* thr   = (const float*)d_in[6];
    const float* gamma = (const float*)d_in[7];
    const float* beta  = (const float*)d_in[8];

    float* out    = (float*)d_out;                    // [MM, DD] LN output
    float* spikes = out + (size_t)MM * DD;            // [MM, DD]
    float* ab_ws  = (float*)d_ws;                     // [MM, 2*DD] interleaved

    dim3 g1(DD / BN, MM / BM);                        // (16, 128)
    k1_gemm_act<<<g1, 256, 0, stream>>>(x, Wd, Wb, bd, bb, A_log, ab_ws);

    dim3 g2(NCHUNK, BB);                              // (32, 8) = 256 blocks, 1/CU
    k23_scan_ln<<<g2, 512, 0, stream>>>(ab_ws, thr, gamma, beta, out, spikes);
}